// Round 13
// baseline (113.909 us; speedup 1.0000x reference)
//
#include <hip/hip_runtime.h>

// out[b,i,j,d] = sum_{k<c} A[b,i,k,d] * B[b,k,j,d]   for i,j < c, else 0
// A: (256,64,64,32) f32, strides: b:131072, i:2048, k:32, d:1
// B: (256,64,64,32) f32, strides: b:131072, k:2048, j:32, d:1
//
// v13 = v12 with ONE change: amdgpu_waves_per_eu(4,4) instead of
// __launch_bounds__(512,4).
// Mechanism: v9/v11/v12 all collapsed to VGPR=64 because the AMDGPU machine
// scheduler's first stage targets MAX occupancy; with only min-waves pinned,
// a 64-VGPR serialized schedule scores better (8 waves/EU) than the 95-VGPR
// pipelined one (4 waves/EU), so it sinks loads and drops the sched groups.
// Occupancy counter (27% ~ 2.2 waves/SIMD) proves that extra occupancy is
// never realized -> pure loss. waves_per_eu(4,4) makes 4 waves/EU the
// TARGET: 65..128 VGPRs become free in its model, letting the K2 register
// pipeline + SGB survive. Primary check: VGPR 64 -> 96+.

#define BATCH 256
#define NN 64
#define ND 32
#define BSTRIDE (NN * NN * ND)   // 131072
#define RSTRIDE (NN * ND)        // 2048
#define ICHUNK 8
#define NITEMS (BATCH * (NN / ICHUNK))  // 2048, item w = b*8 + ic

// ---------------- prologue: per-XCD-bucket counting sort (v8, unchanged) ----
__global__ __launch_bounds__(512) void mp_prologue(
    const int* __restrict__ counts, int* __restrict__ items)
{
    __shared__ int cLds[BATCH];
    __shared__ int hist[8][NN + 1];  // key 0..63 = valid (64-c): whales first; 64 = zero-fill
    __shared__ int offs[8][NN + 1];
    const int tid = (int)threadIdx.x;

    for (int x = tid; x < 8 * (NN + 1); x += 512)
        (&hist[0][0])[x] = 0;
    for (int b = tid; b < BATCH; b += 512) cLds[b] = counts[b];
    __syncthreads();

    for (int w = tid; w < NITEMS; w += 512) {
        const int b = w >> 3, ic = w & 7;
        const int c = cLds[b];
        const int key = (ic * ICHUNK < c) ? (NN - c) : NN;
        atomicAdd(&hist[b & 7][key], 1);
    }
    __syncthreads();

    if (tid < 8) {  // serial 65-entry exclusive scan per bucket
        int acc = 0;
        for (int k = 0; k <= NN; ++k) { offs[tid][k] = acc; acc += hist[tid][k]; }
    }
    __syncthreads();

    for (int w = tid; w < NITEMS; w += 512) {
        const int b = w >> 3, ic = w & 7;
        const int c = cLds[b];
        const int key = (ic * ICHUNK < c) ? (NN - c) : NN;
        const int pos = atomicAdd(&offs[b & 7][key], 1);  // rank within bucket
        items[pos * 8 + (b & 7)] = w;                     // slot%8 == b%8
    }
}

// group load: 2 k-steps (24 scalar loads) into register buffers
#define LOADG(AV, BV, K0)                                                      \
    {                                                                          \
        _Pragma("unroll")                                                      \
        for (int kk = 0; kk < 2; ++kk) {                                       \
            _Pragma("unroll")                                                  \
            for (int ii = 0; ii < ICHUNK; ++ii)                                \
                AV[kk][ii] = Ai[(size_t)ii * RSTRIDE + (size_t)((K0) + kk) * ND]; \
            _Pragma("unroll")                                                  \
            for (int jj = 0; jj < 4; ++jj)                                     \
                BV[kk][jj] = Bb[(size_t)((K0) + kk) * RSTRIDE + jj * ND];      \
        }                                                                      \
    }

// group FMA: 64 fmas consuming one buffer pair
#define FMAG(AV, BV)                                                           \
    {                                                                          \
        _Pragma("unroll")                                                      \
        for (int kk = 0; kk < 2; ++kk)                                         \
            _Pragma("unroll")                                                  \
            for (int ii = 0; ii < ICHUNK; ++ii)                                \
                _Pragma("unroll")                                              \
                for (int jj = 0; jj < 4; ++jj)                                 \
                    acc[ii][jj] = fmaf(AV[kk][ii], BV[kk][jj], acc[ii][jj]);   \
    }

// T19: pin [24 VMEM_READ][64 VALU] per half-iteration (VALU=0x2, VMEM_READ=0x20)
#define SGB2                                                                   \
    {                                                                          \
        __builtin_amdgcn_sched_group_barrier(0x020, 24, 0);                    \
        __builtin_amdgcn_sched_group_barrier(0x002, 64, 0);                    \
    }

// ---------------- main body: 2-deep register pipeline ----------------------
__device__ __forceinline__ void mp_body(
    int b, int ic,
    const float* __restrict__ A, const float* __restrict__ B,
    const int* __restrict__ counts, float* __restrict__ out)
{
    const int i0 = ic << 3;
    const int c  = counts[b];
    const int tid = (int)threadIdx.x;
    const int d  = tid & 31;             // channel
    const int jg = tid >> 5;             // 0..15, group of 4 j's
    const int jb = jg << 2;              // j base

    const size_t base = (size_t)b * BSTRIDE;
    float* __restrict__ Ob = out + base + (size_t)i0 * RSTRIDE + (size_t)jb * ND + d;

    if (i0 >= c) {
        #pragma unroll
        for (int ii = 0; ii < ICHUNK; ++ii)
            #pragma unroll
            for (int jj = 0; jj < 4; ++jj)
                Ob[(size_t)ii * RSTRIDE + jj * ND] = 0.0f;
        return;
    }

    const float* __restrict__ Ai = A + base + (size_t)i0 * RSTRIDE + d;
    const float* __restrict__ Bb = B + base + (size_t)jb * ND + d;

    float acc[ICHUNK][4];
    #pragma unroll
    for (int ii = 0; ii < ICHUNK; ++ii)
        #pragma unroll
        for (int jj = 0; jj < 4; ++jj)
            acc[ii][jj] = 0.0f;

    const bool waveActive = (((tid >> 6) << 3) < c);

    if (waveActive) {
        const int c2 = c & ~1;
        const int ng = c2 >> 1;          // K2 groups
        float aA[2][ICHUNK], bA[2][4];   // ping
        float aB[2][ICHUNK], bB[2][4];   // pong

        if (ng >= 1) {
            LOADG(aA, bA, 0);
            int g = 0;
            #pragma unroll 1
            while (g + 2 <= ng) {
                LOADG(aB, bB, g * 2 + 2);        // prefetch group g+1
                FMAG(aA, bA);                     // consume group g
                SGB2;
                const int kn = (g + 2 < ng) ? (g * 2 + 4) : 0;  // clamp: dummy, rows 0..1 always valid
                LOADG(aA, bA, kn);                // prefetch group g+2 (or dummy)
                FMAG(aB, bB);                     // consume group g+1
                SGB2;
                g += 2;
            }
            if (g < ng) {                         // odd ng: last group in ping
                FMAG(aA, bA);
            }
        }
        // odd-c tail: single k = c2
        if (c & 1) {
            const int k = c2;
            float av[ICHUNK];
            #pragma unroll
            for (int ii = 0; ii < ICHUNK; ++ii)
                av[ii] = Ai[(size_t)ii * RSTRIDE + (size_t)k * ND];
            float bv[4];
            #pragma unroll
            for (int jj = 0; jj < 4; ++jj)
                bv[jj] = Bb[(size_t)k * RSTRIDE + jj * ND];
            #pragma unroll
            for (int ii = 0; ii < ICHUNK; ++ii)
                #pragma unroll
                for (int jj = 0; jj < 4; ++jj)
                    acc[ii][jj] = fmaf(av[ii], bv[jj], acc[ii][jj]);
        }
    }

    #pragma unroll
    for (int ii = 0; ii < ICHUNK; ++ii) {
        const bool iv = (i0 + ii) < c;
        #pragma unroll
        for (int jj = 0; jj < 4; ++jj) {
            const bool v = iv && ((jb + jj) < c);
            Ob[(size_t)ii * RSTRIDE + jj * ND] = v ? acc[ii][jj] : 0.0f;
        }
    }
}

__global__ __attribute__((amdgpu_flat_work_group_size(512, 512), amdgpu_waves_per_eu(4, 4)))
void mp_kernel_sorted(
    const float* __restrict__ A, const float* __restrict__ B,
    const int* __restrict__ counts, float* __restrict__ out,
    const int* __restrict__ items)
{
    const int w = items[blockIdx.x];
    mp_body(w >> 3, w & 7, A, B, counts, out);
}

__global__ __attribute__((amdgpu_flat_work_group_size(512, 512), amdgpu_waves_per_eu(4, 4)))
void mp_kernel_direct(
    const float* __restrict__ A, const float* __restrict__ B,
    const int* __restrict__ counts, float* __restrict__ out)
{
    mp_body(blockIdx.x & (BATCH - 1), blockIdx.x >> 8, A, B, counts, out);
}

extern "C" void kernel_launch(void* const* d_in, const int* in_sizes, int n_in,
                              void* d_out, int out_size, void* d_ws, size_t ws_size,
                              hipStream_t stream)
{
    const float* A      = (const float*)d_in[0];
    const float* B      = (const float*)d_in[1];
    const int*   counts = (const int*)d_in[2];
    float* out = (float*)d_out;

    if (ws_size >= NITEMS * sizeof(int)) {
        int* items = (int*)d_ws;
        mp_prologue<<<dim3(1), dim3(512), 0, stream>>>(counts, items);
        mp_kernel_sorted<<<dim3(NITEMS), dim3(512), 0, stream>>>(A, B, counts, out, items);
    } else {
        mp_kernel_direct<<<dim3(NITEMS), dim3(512), 0, stream>>>(A, B, counts, out);
    }
}